// Round 2
// baseline (182.106 us; speedup 1.0000x reference)
//
#include <hip/hip_runtime.h>

#define N_TOT 8192
#define BHALF 4096
#define D_DIM 512
#define BM 128
#define BK 64
#define NTILE 64          // N_TOT / BM
#define NBLOCKS 2080      // NTILE*(NTILE+1)/2 upper-triangle tiles

// Z is scaled by sqrt(2/ln2) at normalize time, so acc = (2/ln2)*cos and
// exp(2*cos) == exp2(acc) -> bare v_exp_f32, no epilogue muls.
// The positive LOGIT (2*cos) is recovered as acc * ln2.
#define ZSCALE 1.69864368f      // sqrt(2/ln(2))
#define LN2F   0.69314718f

typedef float f32x4 __attribute__((ext_vector_type(4)));
typedef short s16x8 __attribute__((ext_vector_type(8)));  // 8 bf16 in 4 VGPRs

__device__ __forceinline__ unsigned short f2bf(float x) {
    union { float f; unsigned int u; } v; v.f = x;
    unsigned int lsb = (v.u >> 16) & 1u;
    unsigned int r = v.u + 0x7fffu + lsb;   // round-to-nearest-even
    return (unsigned short)(r >> 16);
}

__device__ __forceinline__ float fast_exp2(float x) {
#if __has_builtin(__builtin_amdgcn_exp2f)
    return __builtin_amdgcn_exp2f(x);
#else
    return exp2f(x);
#endif
}

// Kernel 1: row L2-normalize [zjs; zis] * ZSCALE -> bf16 Z.
// Blocks 0..31 zero rowsum; block 32 lane 0 zeroes the ticket counter.
__global__ __launch_bounds__(256) void normalize_kernel(
    const float* __restrict__ zis, const float* __restrict__ zjs,
    unsigned short* __restrict__ zb, float* __restrict__ rowsum,
    unsigned int* __restrict__ done_ctr)
{
    if (blockIdx.x < 32) rowsum[blockIdx.x * 256 + threadIdx.x] = 0.0f;
    if (blockIdx.x == 32 && threadIdx.x == 0) *done_ctr = 0u;
    int wave = threadIdx.x >> 6;
    int lane = threadIdx.x & 63;
    int row  = blockIdx.x * 4 + wave;
    const float* src = (row < BHALF) ? (zjs + (size_t)row * D_DIM)
                                     : (zis + (size_t)(row - BHALF) * D_DIM);
    const float4* src4 = (const float4*)src;
    float4 v0 = src4[lane * 2];
    float4 v1 = src4[lane * 2 + 1];
    float ss = v0.x*v0.x + v0.y*v0.y + v0.z*v0.z + v0.w*v0.w
             + v1.x*v1.x + v1.y*v1.y + v1.z*v1.z + v1.w*v1.w;
    #pragma unroll
    for (int off = 1; off < 64; off <<= 1) ss += __shfl_xor(ss, off);
    float scale = ZSCALE / fmaxf(sqrtf(ss), 1e-8f);

    float vals[8] = {v0.x, v0.y, v0.z, v0.w, v1.x, v1.y, v1.z, v1.w};
    unsigned short u[8];
    #pragma unroll
    for (int i = 0; i < 8; ++i) u[i] = f2bf(vals[i] * scale);
    uint4 o;
    o.x = u[0] | ((unsigned)u[1] << 16);
    o.y = u[2] | ((unsigned)u[3] << 16);
    o.z = u[4] | ((unsigned)u[5] << 16);
    o.w = u[6] | ((unsigned)u[7] << 16);
    ((uint4*)(zb + (size_t)row * D_DIM))[lane] = o;
}

// Kernel 2: upper-triangle 128x128 tiles of exp2(Zs.Zs^T), diag masked.
// Row/col sums -> rowsum[] via symmetry; pos logits on J==I+32 tiles.
// Last block (atomic ticket) computes the final mean in-kernel.
__global__ __launch_bounds__(256, 5) void ntxent_tri_kernel(
    const unsigned short* __restrict__ zb, float* __restrict__ rowsum,
    float* __restrict__ pos_ws, float* __restrict__ out,
    unsigned int* __restrict__ done_ctr)
{
    // XOR-swizzled: 16B unit for (row r, k-chunk c8) lives at unit r*8 + (c8^(r&7))
    // Exactly 32 KB LDS -> 5 blocks/CU (was 33.75 KB -> 4 blocks/CU).
    // rsum/csum overlay onto As AFTER the K-loop (As is dead by then).
    __shared__ unsigned short As[BM * BK];   // 16 KB
    __shared__ unsigned short Bs[BM * BK];   // 16 KB

    const int tid  = threadIdx.x;
    const int wave = tid >> 6;
    const int lane = tid & 63;
    const int cq   = lane & 15;
    const int quad = lane >> 4;
    const int wr   = wave >> 1;    // wave row 0..1
    const int wc   = wave & 1;     // wave col 0..1

    // blockIdx -> (I,J), J-group-major (8 J-panels/group), I-major in group.
    int g = 0, rem = blockIdx.x;
    while (rem >= 64 * g + 36) { rem -= 64 * g + 36; ++g; }
    int I, J;
    if (rem < 64 * g) { I = rem >> 3; J = 8 * g + (rem & 7); }
    else {
        rem -= 64 * g;
        int ii = 0;
        while (rem >= 8 - ii) { rem -= 8 - ii; ++ii; }
        I = 8 * g + ii;
        J = I + rem;
    }
    const int rowbase = I * BM;
    const int colbase = J * BM;
    const bool diagblk = (I == J);
    const bool posblk  = (J == I + NTILE / 2);   // contains (i, i+BHALF) pairs

    // Hoisted staging addresses: swizzled k-chunk is invariant (rnd*32 % 8 == 0).
    const int r0  = tid >> 3;                       // 0..31
    const int c8s = (tid & 7) ^ (r0 & 7);
    const unsigned short* gA[4];
    const unsigned short* gB[4];
    #pragma unroll
    for (int rnd = 0; rnd < 4; ++rnd) {
        int r = rnd * 32 + r0;
        gA[rnd] = zb + (size_t)(rowbase + r) * D_DIM + c8s * 8;
        gB[rnd] = zb + (size_t)(colbase + r) * D_DIM + c8s * 8;
    }

    // Hoisted fragment-read constants.
    int aOff[4], aSw[4], bOff[4], bSw[4];
    #pragma unroll
    for (int t = 0; t < 4; ++t) {
        int ra = wr * 64 + t * 16 + cq;
        int rb = wc * 64 + t * 16 + cq;
        aOff[t] = ra * 64; aSw[t] = ra & 7;
        bOff[t] = rb * 64; bSw[t] = rb & 7;
    }

    f32x4 acc[4][4];
    #pragma unroll
    for (int a = 0; a < 4; ++a)
        #pragma unroll
        for (int b = 0; b < 4; ++b)
            acc[a][b] = (f32x4){0.f, 0.f, 0.f, 0.f};

    for (int kc = 0; kc < D_DIM / BK; ++kc) {
        __syncthreads();   // previous chunk's readers done
        #pragma unroll
        for (int rnd = 0; rnd < 4; ++rnd) {
            __builtin_amdgcn_global_load_lds(
                (const __attribute__((address_space(1))) unsigned int*)gA[rnd],
                (__attribute__((address_space(3))) unsigned int*)&As[(rnd * 256 + tid) * 8],
                16, 0, 0);
            __builtin_amdgcn_global_load_lds(
                (const __attribute__((address_space(1))) unsigned int*)gB[rnd],
                (__attribute__((address_space(3))) unsigned int*)&Bs[(rnd * 256 + tid) * 8],
                16, 0, 0);
            gA[rnd] += BK; gB[rnd] += BK;
        }
        __syncthreads();   // staging complete

        #pragma unroll
        for (int kk = 0; kk < 2; ++kk) {     // two k-steps of 32 per chunk
            s16x8 af[4], bf[4];
            const int c8a = kk * 4 + quad;
            #pragma unroll
            for (int t = 0; t < 4; ++t) {
                af[t] = *(const s16x8*)&As[aOff[t] + ((c8a ^ aSw[t]) << 3)];
                bf[t] = *(const s16x8*)&Bs[bOff[t] + ((c8a ^ bSw[t]) << 3)];
            }
            #pragma unroll
            for (int ar = 0; ar < 4; ++ar)
                #pragma unroll
                for (int bc = 0; bc < 4; ++bc)
                    acc[ar][bc] = __builtin_amdgcn_mfma_f32_16x16x32_bf16(
                        af[ar], bf[bc], acc[ar][bc], 0, 0, 0);
        }
    }

    // pos extraction BEFORE exp: gc == gr + BHALF  <=>  wc==wr, bc==ar, cq==quad*4+reg
    // acc = (2/ln2)*cos -> logit (2*cos) = acc * ln2. Agent-scope store so the
    // fused finalizer (possibly another XCD) sees it.
    if (posblk && wc == wr) {
        #pragma unroll
        for (int ar = 0; ar < 4; ++ar)
            #pragma unroll
            for (int reg = 0; reg < 4; ++reg)
                if (cq == quad * 4 + reg) {
                    int gr = rowbase + wr * 64 + ar * 16 + quad * 4 + reg;
                    __hip_atomic_store(&pos_ws[gr], acc[ar][ar][reg] * LN2F,
                                       __ATOMIC_RELAXED, __HIP_MEMORY_SCOPE_AGENT);
                }
    }

    // exp2 is the native op: one v_exp_f32 per element, zero muls.
    #pragma unroll
    for (int ar = 0; ar < 4; ++ar)
        #pragma unroll
        for (int bc = 0; bc < 4; ++bc)
            #pragma unroll
            for (int reg = 0; reg < 4; ++reg)
                acc[ar][bc][reg] = fast_exp2(acc[ar][bc][reg]);
    if (diagblk && wr == wc) {
        #pragma unroll
        for (int ar = 0; ar < 4; ++ar)
            #pragma unroll
            for (int reg = 0; reg < 4; ++reg)
                if (cq == quad * 4 + reg) acc[ar][ar][reg] = 0.0f;
    }

    // ---- LDS overlay: rsum/csum reuse As (K-loop readers must be done) ----
    float* rsum_lds = (float*)As;         // [0..127]
    float* csum_lds = rsum_lds + BM;      // [128..255]
    __syncthreads();                       // all waves done reading As/Bs
    ((float*)As)[tid] = 0.0f;              // 256 floats = rsum + csum
    __syncthreads();

    // Row sums: sum over 16 cols (bc in-register, cq via shuffle).
    #pragma unroll
    for (int ar = 0; ar < 4; ++ar) {
        float rs[4];
        #pragma unroll
        for (int reg = 0; reg < 4; ++reg) {
            float v = acc[ar][0][reg] + acc[ar][1][reg] + acc[ar][2][reg] + acc[ar][3][reg];
            v += __shfl_xor(v, 1); v += __shfl_xor(v, 2);
            v += __shfl_xor(v, 4); v += __shfl_xor(v, 8);
            rs[reg] = v;
        }
        if (cq == 0) {
            #pragma unroll
            for (int reg = 0; reg < 4; ++reg)
                atomicAdd(&rsum_lds[wr * 64 + ar * 16 + quad * 4 + reg], rs[reg]);
        }
    }

    // Col sums (symmetry): only for off-diagonal blocks.
    if (!diagblk) {
        #pragma unroll
        for (int bc = 0; bc < 4; ++bc) {
            float cs = 0.0f;
            #pragma unroll
            for (int ar = 0; ar < 4; ++ar)
                #pragma unroll
                for (int reg = 0; reg < 4; ++reg)
                    cs += acc[ar][bc][reg];
            cs += __shfl_xor(cs, 16); cs += __shfl_xor(cs, 32);
            if (quad == 0) atomicAdd(&csum_lds[wc * 64 + bc * 16 + cq], cs);
        }
    }

    __syncthreads();
    if (tid < BM) atomicAdd(&rowsum[rowbase + tid], rsum_lds[tid]);
    else if (!diagblk) atomicAdd(&rowsum[colbase + tid - BM], csum_lds[tid - BM]);

    // ---- fused finalize: atomic ticket, last block reduces ----
    __shared__ int lastflag;
    __syncthreads();        // barrier drains vmcnt(0): this block's atomics performed
    if (tid == 0) {
        __threadfence();    // release (L2 writeback) before publishing the ticket
        lastflag = (atomicAdd(done_ctr, 1u) == (unsigned)(NBLOCKS - 1));
    }
    __syncthreads();
    if (lastflag) {
        __threadfence();    // acquire: invalidate stale L1/L2 before reading
        float s = 0.0f;
        for (int r = tid; r < N_TOT; r += 256) {
            float rsv = __hip_atomic_load(&rowsum[r],
                                          __ATOMIC_RELAXED, __HIP_MEMORY_SCOPE_AGENT);
            float pv  = __hip_atomic_load(&pos_ws[r & (BHALF - 1)],
                                          __ATOMIC_RELAXED, __HIP_MEMORY_SCOPE_AGENT);
            s += __logf(rsv) - pv;
        }
        #pragma unroll
        for (int off = 1; off < 64; off <<= 1) s += __shfl_xor(s, off);
        float* red = (float*)Bs;
        if ((tid & 63) == 0) red[tid >> 6] = s;
        __syncthreads();
        if (tid == 0)
            out[0] = (red[0] + red[1] + red[2] + red[3]) * (1.0f / N_TOT);
    }
}

extern "C" void kernel_launch(void* const* d_in, const int* in_sizes, int n_in,
                              void* d_out, int out_size, void* d_ws, size_t ws_size,
                              hipStream_t stream) {
    const float* zis = (const float*)d_in[0];
    const float* zjs = (const float*)d_in[1];
    float* rowsum = (float*)d_ws;                                   // 32 KB
    float* pos_ws = rowsum + N_TOT;                                 // 16 KB
    unsigned int* done_ctr = (unsigned int*)(pos_ws + BHALF);       // 16 B (pad)
    unsigned short* zb = (unsigned short*)(pos_ws + BHALF + 4);     // 8 MB, 16B-aligned
    float* out = (float*)d_out;

    normalize_kernel<<<N_TOT / 4, 256, 0, stream>>>(zis, zjs, zb, rowsum, done_ctr);
    ntxent_tri_kernel<<<NBLOCKS, 256, 0, stream>>>(zb, rowsum, pos_ws, out, done_ctr);
}

// Round 3
// 173.659 us; speedup vs baseline: 1.0486x; 1.0486x over previous
//
#include <hip/hip_runtime.h>

#define N_TOT 8192
#define BHALF 4096
#define D_DIM 512
#define BM 128
#define BK 64
#define NTILE 64          // N_TOT / BM
#define NBLOCKS 2080      // NTILE*(NTILE+1)/2 upper-triangle tiles

// Z is scaled by sqrt(2/ln2) at normalize time, so acc = (2/ln2)*cos and
// exp(2*cos) == exp2(acc) -> bare v_exp_f32, no epilogue muls.
// The positive LOGIT (2*cos) is recovered as acc * ln2.
#define ZSCALE 1.69864368f      // sqrt(2/ln(2))
#define LN2F   0.69314718f

typedef float f32x4 __attribute__((ext_vector_type(4)));
typedef short s16x8 __attribute__((ext_vector_type(8)));  // 8 bf16 in 4 VGPRs

__device__ __forceinline__ unsigned short f2bf(float x) {
    union { float f; unsigned int u; } v; v.f = x;
    unsigned int lsb = (v.u >> 16) & 1u;
    unsigned int r = v.u + 0x7fffu + lsb;   // round-to-nearest-even
    return (unsigned short)(r >> 16);
}

__device__ __forceinline__ float fast_exp2(float x) {
#if __has_builtin(__builtin_amdgcn_exp2f)
    return __builtin_amdgcn_exp2f(x);
#else
    return exp2f(x);
#endif
}

// Kernel 1: row L2-normalize [zjs; zis] * ZSCALE -> bf16 Z.
// Blocks 0..31 zero rowsum; block 32 lane 0 zeroes the ticket counter.
__global__ __launch_bounds__(256) void normalize_kernel(
    const float* __restrict__ zis, const float* __restrict__ zjs,
    unsigned short* __restrict__ zb, float* __restrict__ rowsum,
    unsigned int* __restrict__ done_ctr)
{
    if (blockIdx.x < 32) rowsum[blockIdx.x * 256 + threadIdx.x] = 0.0f;
    if (blockIdx.x == 32 && threadIdx.x == 0) *done_ctr = 0u;
    int wave = threadIdx.x >> 6;
    int lane = threadIdx.x & 63;
    int row  = blockIdx.x * 4 + wave;
    const float* src = (row < BHALF) ? (zjs + (size_t)row * D_DIM)
                                     : (zis + (size_t)(row - BHALF) * D_DIM);
    const float4* src4 = (const float4*)src;
    float4 v0 = src4[lane * 2];
    float4 v1 = src4[lane * 2 + 1];
    float ss = v0.x*v0.x + v0.y*v0.y + v0.z*v0.z + v0.w*v0.w
             + v1.x*v1.x + v1.y*v1.y + v1.z*v1.z + v1.w*v1.w;
    #pragma unroll
    for (int off = 1; off < 64; off <<= 1) ss += __shfl_xor(ss, off);
    float scale = ZSCALE / fmaxf(sqrtf(ss), 1e-8f);

    float vals[8] = {v0.x, v0.y, v0.z, v0.w, v1.x, v1.y, v1.z, v1.w};
    unsigned short u[8];
    #pragma unroll
    for (int i = 0; i < 8; ++i) u[i] = f2bf(vals[i] * scale);
    uint4 o;
    o.x = u[0] | ((unsigned)u[1] << 16);
    o.y = u[2] | ((unsigned)u[3] << 16);
    o.z = u[4] | ((unsigned)u[5] << 16);
    o.w = u[6] | ((unsigned)u[7] << 16);
    ((uint4*)(zb + (size_t)row * D_DIM))[lane] = o;
}

// Kernel 2: upper-triangle 128x128 tiles of exp2(Zs.Zs^T), diag masked.
// Row/col sums -> rowsum[] via symmetry; pos logits on J==I+32 tiles.
// Last block (atomic ticket) computes the final mean in-kernel.
// NOTE: plain __launch_bounds__(256) — the (256,5) cap forced VGPR 96->80 and
// serialized the fragment loads (MfmaUtil 21->11, 2x regression, round 2).
// Compiler lands at ~96 VGPR naturally, which already permits 5 waves/EU;
// with LDS at exactly 32 KB the HW can place 5 blocks/CU.
__global__ __launch_bounds__(256) void ntxent_tri_kernel(
    const unsigned short* __restrict__ zb, float* __restrict__ rowsum,
    float* __restrict__ pos_ws, float* __restrict__ out,
    unsigned int* __restrict__ done_ctr)
{
    // XOR-swizzled: 16B unit for (row r, k-chunk c8) lives at unit r*8 + (c8^(r&7))
    // Exactly 32 KB LDS total -> 5 blocks/CU. rsum/csum AND the ticket flag
    // overlay onto As after the K-loop (As is dead by then).
    __shared__ unsigned short As[BM * BK];   // 16 KB
    __shared__ unsigned short Bs[BM * BK];   // 16 KB

    const int tid  = threadIdx.x;
    const int wave = tid >> 6;
    const int lane = tid & 63;
    const int cq   = lane & 15;
    const int quad = lane >> 4;
    const int wr   = wave >> 1;    // wave row 0..1
    const int wc   = wave & 1;     // wave col 0..1

    // blockIdx -> (I,J), J-group-major (8 J-panels/group), I-major in group.
    int g = 0, rem = blockIdx.x;
    while (rem >= 64 * g + 36) { rem -= 64 * g + 36; ++g; }
    int I, J;
    if (rem < 64 * g) { I = rem >> 3; J = 8 * g + (rem & 7); }
    else {
        rem -= 64 * g;
        int ii = 0;
        while (rem >= 8 - ii) { rem -= 8 - ii; ++ii; }
        I = 8 * g + ii;
        J = I + rem;
    }
    const int rowbase = I * BM;
    const int colbase = J * BM;
    const bool diagblk = (I == J);
    const bool posblk  = (J == I + NTILE / 2);   // contains (i, i+BHALF) pairs

    // Hoisted staging addresses: swizzled k-chunk is invariant (rnd*32 % 8 == 0).
    const int r0  = tid >> 3;                       // 0..31
    const int c8s = (tid & 7) ^ (r0 & 7);
    const unsigned short* gA[4];
    const unsigned short* gB[4];
    #pragma unroll
    for (int rnd = 0; rnd < 4; ++rnd) {
        int r = rnd * 32 + r0;
        gA[rnd] = zb + (size_t)(rowbase + r) * D_DIM + c8s * 8;
        gB[rnd] = zb + (size_t)(colbase + r) * D_DIM + c8s * 8;
    }

    // Hoisted fragment-read constants.
    int aOff[4], aSw[4], bOff[4], bSw[4];
    #pragma unroll
    for (int t = 0; t < 4; ++t) {
        int ra = wr * 64 + t * 16 + cq;
        int rb = wc * 64 + t * 16 + cq;
        aOff[t] = ra * 64; aSw[t] = ra & 7;
        bOff[t] = rb * 64; bSw[t] = rb & 7;
    }

    f32x4 acc[4][4];
    #pragma unroll
    for (int a = 0; a < 4; ++a)
        #pragma unroll
        for (int b = 0; b < 4; ++b)
            acc[a][b] = (f32x4){0.f, 0.f, 0.f, 0.f};

    for (int kc = 0; kc < D_DIM / BK; ++kc) {
        __syncthreads();   // previous chunk's readers done
        #pragma unroll
        for (int rnd = 0; rnd < 4; ++rnd) {
            __builtin_amdgcn_global_load_lds(
                (const __attribute__((address_space(1))) unsigned int*)gA[rnd],
                (__attribute__((address_space(3))) unsigned int*)&As[(rnd * 256 + tid) * 8],
                16, 0, 0);
            __builtin_amdgcn_global_load_lds(
                (const __attribute__((address_space(1))) unsigned int*)gB[rnd],
                (__attribute__((address_space(3))) unsigned int*)&Bs[(rnd * 256 + tid) * 8],
                16, 0, 0);
            gA[rnd] += BK; gB[rnd] += BK;
        }
        __syncthreads();   // staging complete

        #pragma unroll
        for (int kk = 0; kk < 2; ++kk) {     // two k-steps of 32 per chunk
            s16x8 af[4], bf[4];
            const int c8a = kk * 4 + quad;
            #pragma unroll
            for (int t = 0; t < 4; ++t) {
                af[t] = *(const s16x8*)&As[aOff[t] + ((c8a ^ aSw[t]) << 3)];
                bf[t] = *(const s16x8*)&Bs[bOff[t] + ((c8a ^ bSw[t]) << 3)];
            }
            #pragma unroll
            for (int ar = 0; ar < 4; ++ar)
                #pragma unroll
                for (int bc = 0; bc < 4; ++bc)
                    acc[ar][bc] = __builtin_amdgcn_mfma_f32_16x16x32_bf16(
                        af[ar], bf[bc], acc[ar][bc], 0, 0, 0);
        }
    }

    // pos extraction BEFORE exp: gc == gr + BHALF  <=>  wc==wr, bc==ar, cq==quad*4+reg
    // acc = (2/ln2)*cos -> logit (2*cos) = acc * ln2. Agent-scope store so the
    // fused finalizer (possibly another XCD) sees it.
    if (posblk && wc == wr) {
        #pragma unroll
        for (int ar = 0; ar < 4; ++ar)
            #pragma unroll
            for (int reg = 0; reg < 4; ++reg)
                if (cq == quad * 4 + reg) {
                    int gr = rowbase + wr * 64 + ar * 16 + quad * 4 + reg;
                    __hip_atomic_store(&pos_ws[gr], acc[ar][ar][reg] * LN2F,
                                       __ATOMIC_RELAXED, __HIP_MEMORY_SCOPE_AGENT);
                }
    }

    // exp2 is the native op: one v_exp_f32 per element, zero muls.
    #pragma unroll
    for (int ar = 0; ar < 4; ++ar)
        #pragma unroll
        for (int bc = 0; bc < 4; ++bc)
            #pragma unroll
            for (int reg = 0; reg < 4; ++reg)
                acc[ar][bc][reg] = fast_exp2(acc[ar][bc][reg]);
    if (diagblk && wr == wc) {
        #pragma unroll
        for (int ar = 0; ar < 4; ++ar)
            #pragma unroll
            for (int reg = 0; reg < 4; ++reg)
                if (cq == quad * 4 + reg) acc[ar][ar][reg] = 0.0f;
    }

    // ---- LDS overlay: rsum/csum + ticket flag reuse As ----
    float* rsum_lds = (float*)As;         // floats [0..127]
    float* csum_lds = rsum_lds + BM;      // floats [128..255]
    int*   lastflag = (int*)As + 256;     // byte offset 1024, past rsum/csum
    __syncthreads();                       // all waves done reading As/Bs
    ((float*)As)[tid] = 0.0f;              // 256 floats = rsum + csum
    __syncthreads();

    // Row sums: sum over 16 cols (bc in-register, cq via shuffle).
    #pragma unroll
    for (int ar = 0; ar < 4; ++ar) {
        float rs[4];
        #pragma unroll
        for (int reg = 0; reg < 4; ++reg) {
            float v = acc[ar][0][reg] + acc[ar][1][reg] + acc[ar][2][reg] + acc[ar][3][reg];
            v += __shfl_xor(v, 1); v += __shfl_xor(v, 2);
            v += __shfl_xor(v, 4); v += __shfl_xor(v, 8);
            rs[reg] = v;
        }
        if (cq == 0) {
            #pragma unroll
            for (int reg = 0; reg < 4; ++reg)
                atomicAdd(&rsum_lds[wr * 64 + ar * 16 + quad * 4 + reg], rs[reg]);
        }
    }

    // Col sums (symmetry): only for off-diagonal blocks.
    if (!diagblk) {
        #pragma unroll
        for (int bc = 0; bc < 4; ++bc) {
            float cs = 0.0f;
            #pragma unroll
            for (int ar = 0; ar < 4; ++ar)
                #pragma unroll
                for (int reg = 0; reg < 4; ++reg)
                    cs += acc[ar][bc][reg];
            cs += __shfl_xor(cs, 16); cs += __shfl_xor(cs, 32);
            if (quad == 0) atomicAdd(&csum_lds[wc * 64 + bc * 16 + cq], cs);
        }
    }

    __syncthreads();
    if (tid < BM) atomicAdd(&rowsum[rowbase + tid], rsum_lds[tid]);
    else if (!diagblk) atomicAdd(&rowsum[colbase + tid - BM], csum_lds[tid - BM]);

    // ---- fused finalize: atomic ticket, last block reduces ----
    __syncthreads();        // barrier drains vmcnt(0): this block's atomics performed
    if (tid == 0) {
        __threadfence();    // release (L2 writeback) before publishing the ticket
        lastflag[0] = (atomicAdd(done_ctr, 1u) == (unsigned)(NBLOCKS - 1)) ? 1 : 0;
    }
    __syncthreads();
    if (lastflag[0]) {
        __threadfence();    // acquire: invalidate stale L1/L2 before reading
        float s = 0.0f;
        for (int r = tid; r < N_TOT; r += 256) {
            float rsv = __hip_atomic_load(&rowsum[r],
                                          __ATOMIC_RELAXED, __HIP_MEMORY_SCOPE_AGENT);
            float pv  = __hip_atomic_load(&pos_ws[r & (BHALF - 1)],
                                          __ATOMIC_RELAXED, __HIP_MEMORY_SCOPE_AGENT);
            s += __logf(rsv) - pv;
        }
        #pragma unroll
        for (int off = 1; off < 64; off <<= 1) s += __shfl_xor(s, off);
        float* red = (float*)Bs;
        if ((tid & 63) == 0) red[tid >> 6] = s;
        __syncthreads();
        if (tid == 0)
            out[0] = (red[0] + red[1] + red[2] + red[3]) * (1.0f / N_TOT);
    }
}

extern "C" void kernel_launch(void* const* d_in, const int* in_sizes, int n_in,
                              void* d_out, int out_size, void* d_ws, size_t ws_size,
                              hipStream_t stream) {
    const float* zis = (const float*)d_in[0];
    const float* zjs = (const float*)d_in[1];
    float* rowsum = (float*)d_ws;                                   // 32 KB
    float* pos_ws = rowsum + N_TOT;                                 // 16 KB
    unsigned int* done_ctr = (unsigned int*)(pos_ws + BHALF);       // 16 B (pad)
    unsigned short* zb = (unsigned short*)(pos_ws + BHALF + 4);     // 8 MB, 16B-aligned
    float* out = (float*)d_out;

    normalize_kernel<<<N_TOT / 4, 256, 0, stream>>>(zis, zjs, zb, rowsum, done_ctr);
    ntxent_tri_kernel<<<NBLOCKS, 256, 0, stream>>>(zb, rowsum, pos_ws, out, done_ctr);
}

// Round 4
// 151.415 us; speedup vs baseline: 1.2027x; 1.1469x over previous
//
#include <hip/hip_runtime.h>

#define N_TOT 8192
#define BHALF 4096
#define D_DIM 512
#define BM 128
#define BK 64
#define NTILE 64          // N_TOT / BM
#define NBLOCKS 2080      // NTILE*(NTILE+1)/2 upper-triangle tiles

// Z is scaled by sqrt(2/ln2) at normalize time, so acc = (2/ln2)*cos and
// exp(2*cos) == exp2(acc) -> bare v_exp_f32, no epilogue muls.
// The positive LOGIT (2*cos) is recovered as acc * ln2.
#define ZSCALE 1.69864368f      // sqrt(2/ln(2))
#define LN2F   0.69314718f

typedef float f32x4 __attribute__((ext_vector_type(4)));
typedef short s16x8 __attribute__((ext_vector_type(8)));  // 8 bf16 in 4 VGPRs

__device__ __forceinline__ unsigned short f2bf(float x) {
    union { float f; unsigned int u; } v; v.f = x;
    unsigned int lsb = (v.u >> 16) & 1u;
    unsigned int r = v.u + 0x7fffu + lsb;   // round-to-nearest-even
    return (unsigned short)(r >> 16);
}

__device__ __forceinline__ float fast_exp2(float x) {
#if __has_builtin(__builtin_amdgcn_exp2f)
    return __builtin_amdgcn_exp2f(x);
#else
    return exp2f(x);
#endif
}

// Kernel 1: row L2-normalize [zjs; zis] * ZSCALE -> bf16 Z.
// Blocks 0..31 zero rowsum; block 32 lane 0 zeroes the ticket counter.
__global__ __launch_bounds__(256) void normalize_kernel(
    const float* __restrict__ zis, const float* __restrict__ zjs,
    unsigned short* __restrict__ zb, float* __restrict__ rowsum,
    unsigned int* __restrict__ done_ctr)
{
    if (blockIdx.x < 32) rowsum[blockIdx.x * 256 + threadIdx.x] = 0.0f;
    if (blockIdx.x == 32 && threadIdx.x == 0) *done_ctr = 0u;
    int wave = threadIdx.x >> 6;
    int lane = threadIdx.x & 63;
    int row  = blockIdx.x * 4 + wave;
    const float* src = (row < BHALF) ? (zjs + (size_t)row * D_DIM)
                                     : (zis + (size_t)(row - BHALF) * D_DIM);
    const float4* src4 = (const float4*)src;
    float4 v0 = src4[lane * 2];
    float4 v1 = src4[lane * 2 + 1];
    float ss = v0.x*v0.x + v0.y*v0.y + v0.z*v0.z + v0.w*v0.w
             + v1.x*v1.x + v1.y*v1.y + v1.z*v1.z + v1.w*v1.w;
    #pragma unroll
    for (int off = 1; off < 64; off <<= 1) ss += __shfl_xor(ss, off);
    float scale = ZSCALE / fmaxf(sqrtf(ss), 1e-8f);

    float vals[8] = {v0.x, v0.y, v0.z, v0.w, v1.x, v1.y, v1.z, v1.w};
    unsigned short u[8];
    #pragma unroll
    for (int i = 0; i < 8; ++i) u[i] = f2bf(vals[i] * scale);
    uint4 o;
    o.x = u[0] | ((unsigned)u[1] << 16);
    o.y = u[2] | ((unsigned)u[3] << 16);
    o.z = u[4] | ((unsigned)u[5] << 16);
    o.w = u[6] | ((unsigned)u[7] << 16);
    ((uint4*)(zb + (size_t)row * D_DIM))[lane] = o;
}

// Kernel 2: upper-triangle 128x128 tiles of exp2(Zs.Zs^T), diag masked.
// Row/col sums -> rowsum[] via symmetry; pos logits on J==I+32 tiles.
// Last block (relaxed atomic ticket) computes the final mean in-kernel.
//
// FENCE DISCIPLINE (round-3 lesson): NO __threadfence on the per-block path.
// __threadfence = agent seq_cst fence = buffer_wbl2+buffer_inv (L2-wide ops)
// per block -> serialized at the L2 + poisons B-panel L2 reuse -> 2x kernel
// regression (117 vs 63 us, MfmaUtil 21->12). Ordering instead comes from:
//   - rowsum atomicAdd: device-scope, performed at the coherence point;
//   - __syncthreads() before the ticket: compiler emits s_waitcnt vmcnt(0),
//     so this block's atomics are performed before the ticket is issued;
//   - ticket: relaxed agent-scope fetch_add (no implicit cache maintenance);
//   - finalize: agent-scope atomic loads (bypass stale L1/L2), plus ONE
//     acquire __threadfence in the last block only (once per kernel, ~free).
__global__ __launch_bounds__(256) void ntxent_tri_kernel(
    const unsigned short* __restrict__ zb, float* __restrict__ rowsum,
    float* __restrict__ pos_ws, float* __restrict__ out,
    unsigned int* __restrict__ done_ctr)
{
    // XOR-swizzled: 16B unit for (row r, k-chunk c8) lives at unit r*8 + (c8^(r&7))
    // Exactly 32 KB LDS total -> 5 blocks/CU (VGPR 96 allows 5 waves/SIMD).
    // rsum/csum AND the ticket flag overlay onto As after the K-loop.
    __shared__ unsigned short As[BM * BK];   // 16 KB
    __shared__ unsigned short Bs[BM * BK];   // 16 KB

    const int tid  = threadIdx.x;
    const int wave = tid >> 6;
    const int lane = tid & 63;
    const int cq   = lane & 15;
    const int quad = lane >> 4;
    const int wr   = wave >> 1;    // wave row 0..1
    const int wc   = wave & 1;     // wave col 0..1

    // blockIdx -> (I,J), J-group-major (8 J-panels/group), I-major in group.
    int g = 0, rem = blockIdx.x;
    while (rem >= 64 * g + 36) { rem -= 64 * g + 36; ++g; }
    int I, J;
    if (rem < 64 * g) { I = rem >> 3; J = 8 * g + (rem & 7); }
    else {
        rem -= 64 * g;
        int ii = 0;
        while (rem >= 8 - ii) { rem -= 8 - ii; ++ii; }
        I = 8 * g + ii;
        J = I + rem;
    }
    const int rowbase = I * BM;
    const int colbase = J * BM;
    const bool diagblk = (I == J);
    const bool posblk  = (J == I + NTILE / 2);   // contains (i, i+BHALF) pairs

    // Hoisted staging addresses: swizzled k-chunk is invariant (rnd*32 % 8 == 0).
    const int r0  = tid >> 3;                       // 0..31
    const int c8s = (tid & 7) ^ (r0 & 7);
    const unsigned short* gA[4];
    const unsigned short* gB[4];
    #pragma unroll
    for (int rnd = 0; rnd < 4; ++rnd) {
        int r = rnd * 32 + r0;
        gA[rnd] = zb + (size_t)(rowbase + r) * D_DIM + c8s * 8;
        gB[rnd] = zb + (size_t)(colbase + r) * D_DIM + c8s * 8;
    }

    // Hoisted fragment-read constants.
    int aOff[4], aSw[4], bOff[4], bSw[4];
    #pragma unroll
    for (int t = 0; t < 4; ++t) {
        int ra = wr * 64 + t * 16 + cq;
        int rb = wc * 64 + t * 16 + cq;
        aOff[t] = ra * 64; aSw[t] = ra & 7;
        bOff[t] = rb * 64; bSw[t] = rb & 7;
    }

    f32x4 acc[4][4];
    #pragma unroll
    for (int a = 0; a < 4; ++a)
        #pragma unroll
        for (int b = 0; b < 4; ++b)
            acc[a][b] = (f32x4){0.f, 0.f, 0.f, 0.f};

    for (int kc = 0; kc < D_DIM / BK; ++kc) {
        __syncthreads();   // previous chunk's readers done
        #pragma unroll
        for (int rnd = 0; rnd < 4; ++rnd) {
            __builtin_amdgcn_global_load_lds(
                (const __attribute__((address_space(1))) unsigned int*)gA[rnd],
                (__attribute__((address_space(3))) unsigned int*)&As[(rnd * 256 + tid) * 8],
                16, 0, 0);
            __builtin_amdgcn_global_load_lds(
                (const __attribute__((address_space(1))) unsigned int*)gB[rnd],
                (__attribute__((address_space(3))) unsigned int*)&Bs[(rnd * 256 + tid) * 8],
                16, 0, 0);
            gA[rnd] += BK; gB[rnd] += BK;
        }
        __syncthreads();   // staging complete

        #pragma unroll
        for (int kk = 0; kk < 2; ++kk) {     // two k-steps of 32 per chunk
            s16x8 af[4], bf[4];
            const int c8a = kk * 4 + quad;
            #pragma unroll
            for (int t = 0; t < 4; ++t) {
                af[t] = *(const s16x8*)&As[aOff[t] + ((c8a ^ aSw[t]) << 3)];
                bf[t] = *(const s16x8*)&Bs[bOff[t] + ((c8a ^ bSw[t]) << 3)];
            }
            #pragma unroll
            for (int ar = 0; ar < 4; ++ar)
                #pragma unroll
                for (int bc = 0; bc < 4; ++bc)
                    acc[ar][bc] = __builtin_amdgcn_mfma_f32_16x16x32_bf16(
                        af[ar], bf[bc], acc[ar][bc], 0, 0, 0);
        }
    }

    // pos extraction BEFORE exp: gc == gr + BHALF  <=>  wc==wr, bc==ar, cq==quad*4+reg
    // acc = (2/ln2)*cos -> logit (2*cos) = acc * ln2. Agent-scope store so the
    // fused finalizer (possibly another XCD) sees it.
    if (posblk && wc == wr) {
        #pragma unroll
        for (int ar = 0; ar < 4; ++ar)
            #pragma unroll
            for (int reg = 0; reg < 4; ++reg)
                if (cq == quad * 4 + reg) {
                    int gr = rowbase + wr * 64 + ar * 16 + quad * 4 + reg;
                    __hip_atomic_store(&pos_ws[gr], acc[ar][ar][reg] * LN2F,
                                       __ATOMIC_RELAXED, __HIP_MEMORY_SCOPE_AGENT);
                }
    }

    // exp2 is the native op: one v_exp_f32 per element, zero muls.
    #pragma unroll
    for (int ar = 0; ar < 4; ++ar)
        #pragma unroll
        for (int bc = 0; bc < 4; ++bc)
            #pragma unroll
            for (int reg = 0; reg < 4; ++reg)
                acc[ar][bc][reg] = fast_exp2(acc[ar][bc][reg]);
    if (diagblk && wr == wc) {
        #pragma unroll
        for (int ar = 0; ar < 4; ++ar)
            #pragma unroll
            for (int reg = 0; reg < 4; ++reg)
                if (cq == quad * 4 + reg) acc[ar][ar][reg] = 0.0f;
    }

    // ---- LDS overlay: rsum/csum + ticket flag reuse As ----
    float* rsum_lds = (float*)As;         // floats [0..127]
    float* csum_lds = rsum_lds + BM;      // floats [128..255]
    int*   lastflag = (int*)As + 256;     // byte offset 1024, past rsum/csum
    __syncthreads();                       // all waves done reading As/Bs
    ((float*)As)[tid] = 0.0f;              // 256 floats = rsum + csum
    __syncthreads();

    // Row sums: sum over 16 cols (bc in-register, cq via shuffle).
    #pragma unroll
    for (int ar = 0; ar < 4; ++ar) {
        float rs[4];
        #pragma unroll
        for (int reg = 0; reg < 4; ++reg) {
            float v = acc[ar][0][reg] + acc[ar][1][reg] + acc[ar][2][reg] + acc[ar][3][reg];
            v += __shfl_xor(v, 1); v += __shfl_xor(v, 2);
            v += __shfl_xor(v, 4); v += __shfl_xor(v, 8);
            rs[reg] = v;
        }
        if (cq == 0) {
            #pragma unroll
            for (int reg = 0; reg < 4; ++reg)
                atomicAdd(&rsum_lds[wr * 64 + ar * 16 + quad * 4 + reg], rs[reg]);
        }
    }

    // Col sums (symmetry): only for off-diagonal blocks.
    if (!diagblk) {
        #pragma unroll
        for (int bc = 0; bc < 4; ++bc) {
            float cs = 0.0f;
            #pragma unroll
            for (int ar = 0; ar < 4; ++ar)
                #pragma unroll
                for (int reg = 0; reg < 4; ++reg)
                    cs += acc[ar][bc][reg];
            cs += __shfl_xor(cs, 16); cs += __shfl_xor(cs, 32);
            if (quad == 0) atomicAdd(&csum_lds[wc * 64 + bc * 16 + cq], cs);
        }
    }

    __syncthreads();
    if (tid < BM) atomicAdd(&rowsum[rowbase + tid], rsum_lds[tid]);
    else if (!diagblk) atomicAdd(&rowsum[colbase + tid - BM], csum_lds[tid - BM]);

    // ---- fused finalize: relaxed ticket, last block reduces ----
    // The barrier's implicit s_waitcnt vmcnt(0) drains this block's atomics
    // (performed at the device coherence point) before the ticket is issued.
    __syncthreads();
    if (tid == 0) {
        unsigned int prev = __hip_atomic_fetch_add(done_ctr, 1u,
                                __ATOMIC_RELAXED, __HIP_MEMORY_SCOPE_AGENT);
        lastflag[0] = (prev == (unsigned)(NBLOCKS - 1)) ? 1 : 0;
    }
    __syncthreads();
    if (lastflag[0]) {
        __threadfence();    // acquire, ONCE per kernel: invalidate stale caches
        float s = 0.0f;
        for (int r = tid; r < N_TOT; r += 256) {
            float rsv = __hip_atomic_load(&rowsum[r],
                                          __ATOMIC_RELAXED, __HIP_MEMORY_SCOPE_AGENT);
            float pv  = __hip_atomic_load(&pos_ws[r & (BHALF - 1)],
                                          __ATOMIC_RELAXED, __HIP_MEMORY_SCOPE_AGENT);
            s += __logf(rsv) - pv;
        }
        #pragma unroll
        for (int off = 1; off < 64; off <<= 1) s += __shfl_xor(s, off);
        float* red = (float*)Bs;
        if ((tid & 63) == 0) red[tid >> 6] = s;
        __syncthreads();
        if (tid == 0)
            out[0] = (red[0] + red[1] + red[2] + red[3]) * (1.0f / N_TOT);
    }
}

extern "C" void kernel_launch(void* const* d_in, const int* in_sizes, int n_in,
                              void* d_out, int out_size, void* d_ws, size_t ws_size,
                              hipStream_t stream) {
    const float* zis = (const float*)d_in[0];
    const float* zjs = (const float*)d_in[1];
    float* rowsum = (float*)d_ws;                                   // 32 KB
    float* pos_ws = rowsum + N_TOT;                                 // 16 KB
    unsigned int* done_ctr = (unsigned int*)(pos_ws + BHALF);       // 16 B (pad)
    unsigned short* zb = (unsigned short*)(pos_ws + BHALF + 4);     // 8 MB, 16B-aligned
    float* out = (float*)d_out;

    normalize_kernel<<<N_TOT / 4, 256, 0, stream>>>(zis, zjs, zb, rowsum, done_ctr);
    ntxent_tri_kernel<<<NBLOCKS, 256, 0, stream>>>(zb, rowsum, pos_ws, out, done_ctr);
}

// Round 5
// 123.698 us; speedup vs baseline: 1.4722x; 1.2241x over previous
//
#include <hip/hip_runtime.h>

#define N_TOT 8192
#define BHALF 4096
#define D_DIM 512
#define BM 128
#define NTILE 64          // N_TOT / BM
#define NBLOCKS 2080      // NTILE*(NTILE+1)/2 upper-triangle tiles
#define BK2 32            // K per chunk (double-buffered)
#define NCHUNK 16         // D_DIM / BK2
#define BUFSZ (BM * BK2)  // 4096 bf16 elems = 8 KB per buffer

// Z is scaled by sqrt(2/ln2) at normalize time, so acc = (2/ln2)*cos and
// exp(2*cos) == exp2(acc) -> bare v_exp_f32 in the epilogue.
// The positive LOGIT (2*cos) is recovered as acc * ln2.
#define ZSCALE 1.69864368f      // sqrt(2/ln(2))
#define LN2F   0.69314718f

typedef float f32x4 __attribute__((ext_vector_type(4)));
typedef short s16x8 __attribute__((ext_vector_type(8)));  // 8 bf16 in 4 VGPRs

__device__ __forceinline__ unsigned short f2bf(float x) {
    union { float f; unsigned int u; } v; v.f = x;
    unsigned int lsb = (v.u >> 16) & 1u;
    unsigned int r = v.u + 0x7fffu + lsb;   // round-to-nearest-even
    return (unsigned short)(r >> 16);
}

__device__ __forceinline__ float fast_exp2(float x) {
#if __has_builtin(__builtin_amdgcn_exp2f)
    return __builtin_amdgcn_exp2f(x);
#else
    return exp2f(x);
#endif
}

// Kernel 1: row L2-normalize [zjs; zis] * ZSCALE -> bf16 Z.
// Blocks 0..31 zero rowsum.
__global__ __launch_bounds__(256) void normalize_kernel(
    const float* __restrict__ zis, const float* __restrict__ zjs,
    unsigned short* __restrict__ zb, float* __restrict__ rowsum)
{
    if (blockIdx.x < 32) rowsum[blockIdx.x * 256 + threadIdx.x] = 0.0f;
    int wave = threadIdx.x >> 6;
    int lane = threadIdx.x & 63;
    int row  = blockIdx.x * 4 + wave;
    const float* src = (row < BHALF) ? (zjs + (size_t)row * D_DIM)
                                     : (zis + (size_t)(row - BHALF) * D_DIM);
    const float4* src4 = (const float4*)src;
    float4 v0 = src4[lane * 2];
    float4 v1 = src4[lane * 2 + 1];
    float ss = v0.x*v0.x + v0.y*v0.y + v0.z*v0.z + v0.w*v0.w
             + v1.x*v1.x + v1.y*v1.y + v1.z*v1.z + v1.w*v1.w;
    #pragma unroll
    for (int off = 1; off < 64; off <<= 1) ss += __shfl_xor(ss, off);
    float scale = ZSCALE / fmaxf(sqrtf(ss), 1e-8f);

    float vals[8] = {v0.x, v0.y, v0.z, v0.w, v1.x, v1.y, v1.z, v1.w};
    unsigned short u[8];
    #pragma unroll
    for (int i = 0; i < 8; ++i) u[i] = f2bf(vals[i] * scale);
    uint4 o;
    o.x = u[0] | ((unsigned)u[1] << 16);
    o.y = u[2] | ((unsigned)u[3] << 16);
    o.z = u[4] | ((unsigned)u[5] << 16);
    o.w = u[6] | ((unsigned)u[7] << 16);
    ((uint4*)(zb + (size_t)row * D_DIM))[lane] = o;
}

// Kernel 2: upper-triangle 128x128 tiles of exp2(Zs.Zs^T), diag masked.
// Double-buffered BK=32 K-loop with COUNTED vmcnt (T3 minimal pipeline):
// per chunk {STAGE next buf; s_waitcnt vmcnt(4); s_barrier; ds_read+MFMA;
// s_barrier} -- next chunk's loads stay in flight across the compute phase
// (never drained to 0 inside the loop). Tail kept R0-style (3 kernels, plain
// stores): the fused-ticket tail cost ~29us of retirement serialization (R4).
//
// LDS swizzle (64B rows): 16B unit for (row r, k-unit c8) lives at unit
// r*4 + (c8 ^ ((r>>1)&3)); fragment reads then hit 8 distinct 16B slots per
// 16 lanes -> 2-way aliasing (free). Staging dest is linear in tid
// (global_load_lds requirement); the global SOURCE address is pre-swizzled.
__global__ __launch_bounds__(256) void ntxent_tri_kernel(
    const unsigned short* __restrict__ zb, float* __restrict__ rowsum,
    float* __restrict__ pos_ws)
{
    __shared__ unsigned short As[2 * BUFSZ];   // 16 KB (2 buffers)
    __shared__ unsigned short Bs[2 * BUFSZ];   // 16 KB
    // rsum/csum overlay onto As after the K-loop -> total LDS 32 KB.

    const int tid  = threadIdx.x;
    const int wave = tid >> 6;
    const int lane = tid & 63;
    const int cq   = lane & 15;
    const int quad = lane >> 4;
    const int wr   = wave >> 1;    // wave row 0..1
    const int wc   = wave & 1;     // wave col 0..1

    // blockIdx -> (I,J), J-group-major (8 J-panels/group), I-major in group.
    int g = 0, rem = blockIdx.x;
    while (rem >= 64 * g + 36) { rem -= 64 * g + 36; ++g; }
    int I, J;
    if (rem < 64 * g) { I = rem >> 3; J = 8 * g + (rem & 7); }
    else {
        rem -= 64 * g;
        int ii = 0;
        while (rem >= 8 - ii) { rem -= 8 - ii; ++ii; }
        I = 8 * g + ii;
        J = I + rem;
    }
    const int rowbase = I * BM;
    const int colbase = J * BM;
    const bool diagblk = (I == J);
    const bool posblk  = (J == I + NTILE / 2);   // contains (i, i+BHALF) pairs

    // Staging: thread tid, round rnd covers row r = rnd*64 + (tid>>2),
    // LDS unit u = tid&3. The global k-unit that belongs there is
    // c8 = u ^ ((r>>1)&3) = (tid&3) ^ ((tid>>3)&3)  (rnd-invariant).
    const int c8s = (tid & 3) ^ ((tid >> 3) & 3);
    const unsigned short* pA0 = zb + (size_t)(rowbase + (tid >> 2)) * D_DIM + c8s * 8;
    const unsigned short* pA1 = pA0 + (size_t)64 * D_DIM;
    const unsigned short* pB0 = zb + (size_t)(colbase + (tid >> 2)) * D_DIM + c8s * 8;
    const unsigned short* pB1 = pB0 + (size_t)64 * D_DIM;
    const int dst0 = tid * 8;            // elems; round 0
    const int dst1 = (256 + tid) * 8;    // elems; round 1

    // Fragment reads: lane wants k-unit 'quad' of row ra; it lives at LDS
    // unit u = quad ^ ((ra>>1)&3) = quad ^ ((cq>>1)&3)  (t/wr-invariant).
    const int swz = (quad ^ ((cq >> 1) & 3)) << 3;   // elem offset in row
    int aOff[4], bOff[4];
    #pragma unroll
    for (int t = 0; t < 4; ++t) {
        aOff[t] = (wr * 64 + t * 16 + cq) * BK2 + swz;
        bOff[t] = (wc * 64 + t * 16 + cq) * BK2 + swz;
    }

    f32x4 acc[4][4];
    #pragma unroll
    for (int a = 0; a < 4; ++a)
        #pragma unroll
        for (int b = 0; b < 4; ++b)
            acc[a][b] = (f32x4){0.f, 0.f, 0.f, 0.f};

#define STAGE(buf) do {                                                          \
    const int dbase = (buf) * BUFSZ;                                             \
    __builtin_amdgcn_global_load_lds(                                            \
        (const __attribute__((address_space(1))) unsigned int*)pA0,              \
        (__attribute__((address_space(3))) unsigned int*)&As[dbase + dst0],      \
        16, 0, 0);                                                               \
    __builtin_amdgcn_global_load_lds(                                            \
        (const __attribute__((address_space(1))) unsigned int*)pA1,              \
        (__attribute__((address_space(3))) unsigned int*)&As[dbase + dst1],      \
        16, 0, 0);                                                               \
    __builtin_amdgcn_global_load_lds(                                            \
        (const __attribute__((address_space(1))) unsigned int*)pB0,              \
        (__attribute__((address_space(3))) unsigned int*)&Bs[dbase + dst0],      \
        16, 0, 0);                                                               \
    __builtin_amdgcn_global_load_lds(                                            \
        (const __attribute__((address_space(1))) unsigned int*)pB1,              \
        (__attribute__((address_space(3))) unsigned int*)&Bs[dbase + dst1],      \
        16, 0, 0);                                                               \
    pA0 += BK2; pA1 += BK2; pB0 += BK2; pB1 += BK2;                              \
} while (0)

#define COMPUTE(buf) do {                                                        \
    const int cbase = (buf) * BUFSZ;                                             \
    s16x8 af[4], bf[4];                                                          \
    _Pragma("unroll")                                                            \
    for (int t = 0; t < 4; ++t) {                                                \
        af[t] = *(const s16x8*)&As[cbase + aOff[t]];                             \
        bf[t] = *(const s16x8*)&Bs[cbase + bOff[t]];                             \
    }                                                                            \
    _Pragma("unroll")                                                            \
    for (int ar = 0; ar < 4; ++ar)                                               \
        _Pragma("unroll")                                                        \
        for (int bc = 0; bc < 4; ++bc)                                           \
            acc[ar][bc] = __builtin_amdgcn_mfma_f32_16x16x32_bf16(               \
                af[ar], bf[bc], acc[ar][bc], 0, 0, 0);                           \
} while (0)

    // Prologue: stage chunk 0 into buffer 0.
    STAGE(0);
    #pragma unroll
    for (int kc = 0; kc < NCHUNK - 1; ++kc) {
        STAGE((kc + 1) & 1);                              // next chunk in flight
        asm volatile("s_waitcnt vmcnt(4)" ::: "memory");  // my cur-chunk loads done
        __builtin_amdgcn_s_barrier();                     // everyone's done
        __builtin_amdgcn_sched_barrier(0);                // no hoisting across
        COMPUTE(kc & 1);
        __builtin_amdgcn_s_barrier();                     // readers done; cur buf free
    }
    // Tail chunk (15): nothing left to stage; drain.
    asm volatile("s_waitcnt vmcnt(0)" ::: "memory");
    __builtin_amdgcn_s_barrier();
    __builtin_amdgcn_sched_barrier(0);
    COMPUTE((NCHUNK - 1) & 1);

    // pos extraction BEFORE exp: gc == gr + BHALF  <=>  wc==wr, bc==ar, cq==quad*4+reg
    // acc = (2/ln2)*cos -> logit (2*cos) = acc * ln2. Plain store: the separate
    // finalize kernel launch is the synchronization point.
    if (posblk && wc == wr) {
        #pragma unroll
        for (int ar = 0; ar < 4; ++ar)
            #pragma unroll
            for (int reg = 0; reg < 4; ++reg)
                if (cq == quad * 4 + reg) {
                    int gr = rowbase + wr * 64 + ar * 16 + quad * 4 + reg;
                    pos_ws[gr] = acc[ar][ar][reg] * LN2F;
                }
    }

    // exp2 is the native op: one v_exp_f32 per element.
    #pragma unroll
    for (int ar = 0; ar < 4; ++ar)
        #pragma unroll
        for (int bc = 0; bc < 4; ++bc)
            #pragma unroll
            for (int reg = 0; reg < 4; ++reg)
                acc[ar][bc][reg] = fast_exp2(acc[ar][bc][reg]);
    if (diagblk && wr == wc) {
        #pragma unroll
        for (int ar = 0; ar < 4; ++ar)
            #pragma unroll
            for (int reg = 0; reg < 4; ++reg)
                if (cq == quad * 4 + reg) acc[ar][ar][reg] = 0.0f;
    }

    // ---- LDS overlay: rsum/csum reuse As (K-loop readers all done) ----
    float* rsum_lds = (float*)As;         // floats [0..127]
    float* csum_lds = rsum_lds + BM;      // floats [128..255]
    __syncthreads();                       // all waves past their LDS reads
    ((float*)As)[tid] = 0.0f;              // 256 floats = rsum + csum
    __syncthreads();

    // Row sums: sum over 16 cols (bc in-register, cq via shuffle).
    #pragma unroll
    for (int ar = 0; ar < 4; ++ar) {
        float rs[4];
        #pragma unroll
        for (int reg = 0; reg < 4; ++reg) {
            float v = acc[ar][0][reg] + acc[ar][1][reg] + acc[ar][2][reg] + acc[ar][3][reg];
            v += __shfl_xor(v, 1); v += __shfl_xor(v, 2);
            v += __shfl_xor(v, 4); v += __shfl_xor(v, 8);
            rs[reg] = v;
        }
        if (cq == 0) {
            #pragma unroll
            for (int reg = 0; reg < 4; ++reg)
                atomicAdd(&rsum_lds[wr * 64 + ar * 16 + quad * 4 + reg], rs[reg]);
        }
    }

    // Col sums (symmetry): only for off-diagonal blocks.
    if (!diagblk) {
        #pragma unroll
        for (int bc = 0; bc < 4; ++bc) {
            float cs = 0.0f;
            #pragma unroll
            for (int ar = 0; ar < 4; ++ar)
                #pragma unroll
                for (int reg = 0; reg < 4; ++reg)
                    cs += acc[ar][bc][reg];
            cs += __shfl_xor(cs, 16); cs += __shfl_xor(cs, 32);
            if (quad == 0) atomicAdd(&csum_lds[wc * 64 + bc * 16 + cq], cs);
        }
    }

    __syncthreads();
    if (tid < BM) atomicAdd(&rowsum[rowbase + tid], rsum_lds[tid]);
    else if (!diagblk) atomicAdd(&rowsum[colbase + tid - BM], csum_lds[tid - BM]);
#undef STAGE
#undef COMPUTE
}

// Kernel 3: single block. mean_r( log(rowsum[r]) - pos[r & (BHALF-1)] ).
__global__ __launch_bounds__(256) void finalize_kernel(
    const float* __restrict__ rowsum, const float* __restrict__ pos_ws,
    float* __restrict__ out)
{
    __shared__ float red[4];
    float s = 0.0f;
    for (int r = threadIdx.x; r < N_TOT; r += 256)
        s += __logf(rowsum[r]) - pos_ws[r & (BHALF - 1)];
    #pragma unroll
    for (int off = 1; off < 64; off <<= 1) s += __shfl_xor(s, off);
    int wave = threadIdx.x >> 6, lane = threadIdx.x & 63;
    if (lane == 0) red[wave] = s;
    __syncthreads();
    if (threadIdx.x == 0)
        out[0] = (red[0] + red[1] + red[2] + red[3]) * (1.0f / N_TOT);
}

extern "C" void kernel_launch(void* const* d_in, const int* in_sizes, int n_in,
                              void* d_out, int out_size, void* d_ws, size_t ws_size,
                              hipStream_t stream) {
    const float* zis = (const float*)d_in[0];
    const float* zjs = (const float*)d_in[1];
    float* rowsum = (float*)d_ws;                                   // 32 KB
    float* pos_ws = rowsum + N_TOT;                                 // 16 KB
    unsigned short* zb = (unsigned short*)(pos_ws + BHALF);         // 8 MB, 16B-aligned
    float* out = (float*)d_out;

    normalize_kernel<<<N_TOT / 4, 256, 0, stream>>>(zis, zjs, zb, rowsum);
    ntxent_tri_kernel<<<NBLOCKS, 256, 0, stream>>>(zb, rowsum, pos_ws);
    finalize_kernel<<<1, 256, 0, stream>>>(rowsum, pos_ws, out);
}